// Round 2
// baseline (64996.271 us; speedup 1.0000x reference)
//
#include <hip/hip_runtime.h>
#include <hip/hip_bf16.h>
#include <math.h>

// Problem dims
#define B_   128
#define T_   800
#define H_   512
#define K_   10
#define C_   80
#define U_   64
#define IN_  3
#define SDIM (H_ + C_)   // 592 = h(512) | window(80)

// Decomposition
#define NG   4           // batch groups (independent recurrences, 32 batches each)
#define BPG  128         // blocks per group (each owns 4 hidden units = 16 gate rows)
#define BT   32          // batches per group
#define RPB  16          // gate rows per block (4 units x 4 gates i,f,g,o)
#define UPB  4           // units per block
#define NT   256         // threads per block

// ws layout (float offsets)
#define WS_ST    0                                   // sT[2][SDIM][B_]  double-buffered state
#define WS_C     (2*SDIM*B_)                         // cpriv[512 blocks][128]
#define WS_KAP   (WS_C + NG*BPG*BT*UPB)              // kappa[10][128]
#define WS_BAR   (WS_KAP + K_*B_)                    // per-group counters (256B apart)
#define WS_TOTAL (WS_BAR + NG*64)

// out layout (f32 elements): h_seq | w_seq | phi_seq
#define OFF_H    0ull
#define OFF_W    ((size_t)B_ * T_ * H_)              // 52,428,800
#define OFF_PHI  (OFF_W + (size_t)B_ * T_ * C_)      // 60,620,800

__device__ __forceinline__ void bar_arrive(unsigned* p) {
  __hip_atomic_fetch_add(p, 1u, __ATOMIC_RELEASE, __HIP_MEMORY_SCOPE_AGENT);
}
__device__ __forceinline__ void bar_wait(unsigned* p, unsigned target) {
  while (__hip_atomic_load(p, __ATOMIC_ACQUIRE, __HIP_MEMORY_SCOPE_AGENT) < target)
    __builtin_amdgcn_s_sleep(2);
}
__device__ __forceinline__ float sigmoidf_(float v) { return 1.0f / (1.0f + expf(-v)); }

__global__ void __launch_bounds__(NT, 2)
init_ws_kernel(float* __restrict__ ws) {
  size_t i = (size_t)blockIdx.x * NT + threadIdx.x;
  const size_t n = (size_t)WS_TOTAL;
  const size_t stride = (size_t)gridDim.x * NT;
  for (; i < n; i += stride) ws[i] = 0.0f;
}

__global__ void __launch_bounds__(NT, 2)
graves_kernel(const float* __restrict__ x,       // [B][T][IN]
              const int*   __restrict__ sent,    // [B][U]
              const float* __restrict__ smask,   // [B][U]
              const float* __restrict__ W_ih,    // [2048][83]
              const float* __restrict__ W_hh,    // [2048][512]
              const float* __restrict__ b_ih,    // [2048]
              const float* __restrict__ b_hh,    // [2048]
              const float* __restrict__ W_win,   // [30][512]
              const float* __restrict__ b_win,   // [30]
              float* __restrict__ out,
              float* __restrict__ ws)
{
  const int tid = threadIdx.x;
  const int bid = blockIdx.x;
  const int g   = bid >> 7;          // group (blocks of a group are contiguous -> co-resident even at 1 blk/CU)
  const int ub  = bid & (BPG - 1);
  const int b0  = g * BT;
  const int u0  = ub * UPB;

  float* sT    = ws + WS_ST;
  float* cpriv = ws + WS_C + (size_t)bid * (BT * UPB);
  float* kap   = ws + WS_KAP;
  unsigned* c1 = (unsigned*)(ws + WS_BAR) + (size_t)g * 64;  // h-ready barrier
  unsigned* c2 = c1 + 32;                                     // window-ready counter (32 arrivals/step)

  __shared__ __align__(16) float wlds[SDIM][RPB]; // weights [k][r], k-major for float4 reads
  __shared__ float xwb[RPB][4];                   // x-weights[3] + bias
  __shared__ float red[NT][17];                   // k-split partials, pad 17 -> conflict-free
  __shared__ float gl[RPB][BT];
  __shared__ float hl[H_];
  __shared__ float pred[8][30];
  __shared__ float pl[30];
  __shared__ float abk[3][K_];                    // alpha, beta, kappa
  __shared__ float phim[U_];                      // phi * mask
  __shared__ int   sentl[U_];
  __shared__ float maskl[U_];

  // ---- one-time weight staging: local row r = uu*4 + gate; global row = gate*512 + u0+uu ----
  for (int idx = tid; idx < SDIM * RPB; idx += NT) {
    const int k = idx >> 4, r = idx & 15;
    const int uu = r >> 2, gate = r & 3;
    const int gr = gate * H_ + u0 + uu;
    wlds[k][r] = (k < H_) ? W_hh[(size_t)gr * H_ + k]
                          : W_ih[(size_t)gr * (IN_ + C_) + IN_ + (k - H_)];
  }
  if (tid < RPB) {
    const int uu = tid >> 2, gate = tid & 3, gr = gate * H_ + u0 + uu;
    xwb[tid][0] = W_ih[(size_t)gr * (IN_ + C_) + 0];
    xwb[tid][1] = W_ih[(size_t)gr * (IN_ + C_) + 1];
    xwb[tid][2] = W_ih[(size_t)gr * (IN_ + C_) + 2];
    xwb[tid][3] = b_ih[gr] + b_hh[gr];
  }
  const bool isWB = (ub < BT);      // first 32 blocks of each group own one batch's window pipeline
  const int  wb_b = b0 + ub;
  if (isWB && tid < U_) {
    sentl[tid] = sent[wb_b * U_ + tid];
    maskl[tid] = smask[wb_b * U_ + tid];
  }
  __syncthreads();

  const int rt  = tid & 3;          // row tile: rows 4*rt..4*rt+3
  const int bt  = (tid >> 2) & 7;   // batch tile: batches 4*bt..4*bt+3
  const int ks  = tid >> 5;         // k split (8 chunks)
  const int myb = b0 + 4 * bt;

  for (int t = 0; t < T_; ++t) {
    const int p = t & 1;
    const float* sIn = sT + (size_t)p * (SDIM * B_);
    float*      sOut = sT + (size_t)(1 - p) * (SDIM * B_);

    float acc[4][4];
    #pragma unroll
    for (int i = 0; i < 4; ++i) {
      #pragma unroll
      for (int j = 0; j < 4; ++j) acc[i][j] = 0.0f;
    }

    // ---- A1p1: recurrent h-part, k in [0,512). Needs only bar1(t-1); overlaps with window(t-1). ----
    {
      const float* sp = sIn + myb;
      const int k0 = ks * (H_ / 8);
      #pragma unroll 4
      for (int k = k0; k < k0 + H_ / 8; ++k) {
        const float4 s4 = *(const float4*)(sp + (size_t)k * B_);
        const float4 w4 = *(const float4*)(&wlds[k][4 * rt]);
        const float sv[4] = {s4.x, s4.y, s4.z, s4.w};
        const float wv[4] = {w4.x, w4.y, w4.z, w4.w};
        #pragma unroll
        for (int i = 0; i < 4; ++i) {
          #pragma unroll
          for (int j = 0; j < 4; ++j) acc[i][j] = fmaf(wv[i], sv[j], acc[i][j]);
        }
      }
    }

    // ---- wait until window_{t-1} published ----
    if (tid == 0) bar_wait(c2, (unsigned)(BT * t));
    __syncthreads();

    // ---- A1p2: window part, k in [512,592) ----
    {
      const float* sp = sIn + myb;
      const int k0 = H_ + ks * (C_ / 8);
      #pragma unroll
      for (int k = k0; k < k0 + C_ / 8; ++k) {
        const float4 s4 = *(const float4*)(sp + (size_t)k * B_);
        const float4 w4 = *(const float4*)(&wlds[k][4 * rt]);
        const float sv[4] = {s4.x, s4.y, s4.z, s4.w};
        const float wv[4] = {w4.x, w4.y, w4.z, w4.w};
        #pragma unroll
        for (int i = 0; i < 4; ++i) {
          #pragma unroll
          for (int j = 0; j < 4; ++j) acc[i][j] = fmaf(wv[i], sv[j], acc[i][j]);
        }
      }
    }

    // ---- A2: stash k-split partials ----
    #pragma unroll
    for (int i = 0; i < 4; ++i) {
      #pragma unroll
      for (int j = 0; j < 4; ++j) red[tid][i * 4 + j] = acc[i][j];
    }
    __syncthreads();

    // ---- A3: reduce over 8 k-splits + bias + x-term ----
    for (int it = tid; it < RPB * BT; it += NT) {
      const int r = it >> 5, b = it & 31;
      const int base = (r >> 2) + 4 * (b >> 2);
      const int e = (r & 3) * 4 + (b & 3);
      float v = xwb[r][3];
      #pragma unroll
      for (int kq = 0; kq < 8; ++kq) v += red[base + 32 * kq][e];
      const float* xp = x + ((size_t)(b0 + b) * T_ + t) * IN_;
      v = fmaf(xwb[r][0], xp[0], v);
      v = fmaf(xwb[r][1], xp[1], v);
      v = fmaf(xwb[r][2], xp[2], v);
      gl[r][b] = v;
    }
    __syncthreads();

    // ---- A4: LSTM pointwise (128 items: 32 batches x 4 units) ----
    if (tid < BT * UPB) {
      const int b = tid >> 2, uu = tid & 3;
      const float iv = sigmoidf_(gl[uu * 4 + 0][b]);
      const float fv = sigmoidf_(gl[uu * 4 + 1][b]);
      const float gv = tanhf(gl[uu * 4 + 2][b]);
      const float ov = sigmoidf_(gl[uu * 4 + 3][b]);
      const float cv = fmaf(fv, cpriv[b * 4 + uu], iv * gv);
      cpriv[b * 4 + uu] = cv;
      const float hv = ov * tanhf(cv);
      sOut[(size_t)(u0 + uu) * B_ + b0 + b] = hv;
      out[OFF_H + ((size_t)(b0 + b) * T_ + t) * H_ + (u0 + uu)] = hv;
    }
    __syncthreads();

    // ---- bar1: all h_t of this group visible ----
    if (tid == 0) {
      bar_arrive(c1);
      bar_wait(c1, (unsigned)(BPG * (t + 1)));
    }
    __syncthreads();

    // ---- Phase B: window pipeline for one batch (32 blocks/group); others fall through to next A1p1 ----
    if (isWB) {
      for (int k = tid; k < H_; k += NT) hl[k] = sOut[(size_t)k * B_ + wb_b];
      __syncthreads();
      if (tid < 240) {                       // p = h @ W_win.T, 30 rows x 8 k-chunks
        const int j = tid % 30, kc = tid / 30;
        const float* wr = W_win + (size_t)j * H_ + kc * 64;
        const float* hp = hl + kc * 64;
        float s = 0.0f;
        #pragma unroll
        for (int k2 = 0; k2 < 64; k2 += 4) {
          const float4 w4 = *(const float4*)(wr + k2);
          s = fmaf(w4.x, hp[k2 + 0], s);
          s = fmaf(w4.y, hp[k2 + 1], s);
          s = fmaf(w4.z, hp[k2 + 2], s);
          s = fmaf(w4.w, hp[k2 + 3], s);
        }
        pred[kc][j] = s;
      }
      __syncthreads();
      if (tid < 30) {
        float s = b_win[tid];
        #pragma unroll
        for (int kc = 0; kc < 8; ++kc) s += pred[kc][tid];
        pl[tid] = s;
      }
      __syncthreads();
      if (tid < K_) {
        abk[0][tid] = expf(pl[tid]);                       // alpha
        abk[1][tid] = expf(pl[K_ + tid]);                  // beta
        const float kv = kap[tid * B_ + wb_b] + expf(pl[2 * K_ + tid]);
        kap[tid * B_ + wb_b] = kv;                         // kappa state
        abk[2][tid] = kv;
      }
      __syncthreads();
      if (tid < U_) {                                      // phi[u]
        const float fu = (float)tid;
        float s = 0.0f;
        #pragma unroll
        for (int j2 = 0; j2 < K_; ++j2) {
          const float d = abk[2][j2] - fu;
          s = fmaf(abk[0][j2], expf(-abk[1][j2] * d * d), s);
        }
        phim[tid] = s * maskl[tid];
        out[OFF_PHI + ((size_t)wb_b * T_ + t) * U_ + tid] = s;
      }
      __syncthreads();
      if (tid < C_) {                                      // window[c] (deterministic gather)
        float wv = 0.0f;
        #pragma unroll
        for (int u = 0; u < U_; ++u) wv += (sentl[u] == tid) ? phim[u] : 0.0f;
        sOut[(size_t)(H_ + tid) * B_ + wb_b] = wv;
        out[OFF_W + ((size_t)wb_b * T_ + t) * C_ + tid] = wv;
      }
      __syncthreads();
      if (tid == 0) bar_arrive(c2);
    }
  }
}

extern "C" void kernel_launch(void* const* d_in, const int* in_sizes, int n_in,
                              void* d_out, int out_size, void* d_ws, size_t ws_size,
                              hipStream_t stream) {
  const float* x     = (const float*)d_in[0];
  const int*   sent  = (const int*)  d_in[1];
  const float* smask = (const float*)d_in[2];
  const float* W_ih  = (const float*)d_in[3];
  const float* W_hh  = (const float*)d_in[4];
  const float* b_ih  = (const float*)d_in[5];
  const float* b_hh  = (const float*)d_in[6];
  const float* W_win = (const float*)d_in[7];
  const float* b_win = (const float*)d_in[8];
  float* ws = (float*)d_ws;
  float* out = (float*)d_out;

  hipLaunchKernelGGL(init_ws_kernel, dim3(512), dim3(NT), 0, stream, ws);
  hipLaunchKernelGGL(graves_kernel, dim3(NG * BPG), dim3(NT), 0, stream,
                     x, sent, smask, W_ih, W_hh, b_ih, b_hh, W_win, b_win, out, ws);
}

// Round 3
// 16288.165 us; speedup vs baseline: 3.9904x; 3.9904x over previous
//
#include <hip/hip_runtime.h>
#include <hip/hip_bf16.h>
#include <math.h>

// Problem dims
#define B_   128
#define T_   800
#define H_   512
#define K_   10
#define C_   80
#define U_   64
#define IN_  3
#define SDIM (H_ + C_)   // 592 = h(512) | window(80)

// Decomposition
#define NG   4           // batch groups (independent recurrences, 32 batches each)
#define BPG  128         // blocks per group (each owns 4 hidden units = 16 gate rows)
#define BT   32          // batches per group
#define RPB  16          // gate rows per block (4 units x 4 gates i,f,g,o)
#define UPB  4           // units per block
#define NT   256         // threads per block

// ws layout (float offsets)
#define WS_ST    0                                   // sT[2][SDIM][B_]  double-buffered state
#define WS_HROW  (2*SDIM*B_)                         // hrow[B_][H_] transposed h (bypass-written)
#define WS_C     (WS_HROW + B_*H_)                   // cpriv[512 blocks][128]
#define WS_KAP   (WS_C + NG*BPG*BT*UPB)              // kappa[10][128]
#define WS_BAR   (WS_KAP + K_*B_)                    // per-group flag lines: 12 lines x 128B
#define WS_TOTAL (WS_BAR + NG*12*32)

// out layout (f32 elements): h_seq | w_seq | phi_seq
#define OFF_H    0ull
#define OFF_W    ((size_t)B_ * T_ * H_)              // 52,428,800
#define OFF_PHI  (OFF_W + (size_t)B_ * T_ * C_)      // 60,620,800

// ---- sync primitives: relaxed atomics + manual fences (no per-op L2 flush) ----
__device__ __forceinline__ void st_bypass(float* p, float v) {
  asm volatile("global_store_dword %0, %1, off sc0 sc1" :: "v"(p), "v"(v) : "memory");
}
__device__ __forceinline__ void fence_vm() {
  asm volatile("s_waitcnt vmcnt(0)" ::: "memory");
}
__device__ __forceinline__ void flag_add(unsigned* p) {
  __hip_atomic_fetch_add(p, 1u, __ATOMIC_RELAXED, __HIP_MEMORY_SCOPE_AGENT);
}
__device__ __forceinline__ unsigned flag_sum8(unsigned* base) {
  unsigned s = 0;
  #pragma unroll
  for (int i = 0; i < 8; ++i)
    s += __hip_atomic_load(base + i * 32, __ATOMIC_RELAXED, __HIP_MEMORY_SCOPE_AGENT);
  return s;
}
__device__ __forceinline__ unsigned flag_sum4(unsigned* base) {
  unsigned s = 0;
  #pragma unroll
  for (int i = 0; i < 4; ++i)
    s += __hip_atomic_load(base + i * 32, __ATOMIC_RELAXED, __HIP_MEMORY_SCOPE_AGENT);
  return s;
}
__device__ __forceinline__ void acq_fence(unsigned* p) {
  (void)__hip_atomic_load(p, __ATOMIC_ACQUIRE, __HIP_MEMORY_SCOPE_AGENT);  // one precise inv
}
__device__ __forceinline__ float sigmoidf_(float v) { return 1.0f / (1.0f + expf(-v)); }

__global__ void __launch_bounds__(NT, 2)
init_ws_kernel(float* __restrict__ ws) {
  size_t i = (size_t)blockIdx.x * NT + threadIdx.x;
  const size_t n = (size_t)WS_TOTAL;
  const size_t stride = (size_t)gridDim.x * NT;
  for (; i < n; i += stride) ws[i] = 0.0f;
}

__global__ void __launch_bounds__(NT, 2)
graves_kernel(const float* __restrict__ x,       // [B][T][IN]
              const int*   __restrict__ sent,    // [B][U]
              const float* __restrict__ smask,   // [B][U]
              const float* __restrict__ W_ih,    // [2048][83]
              const float* __restrict__ W_hh,    // [2048][512]
              const float* __restrict__ b_ih,    // [2048]
              const float* __restrict__ b_hh,    // [2048]
              const float* __restrict__ W_win,   // [30][512]
              const float* __restrict__ b_win,   // [30]
              float* __restrict__ out,
              float* __restrict__ ws)
{
  const int tid = threadIdx.x;
  const int bid = blockIdx.x;
  const int g   = bid >> 7;
  const int ub  = bid & (BPG - 1);
  const int b0  = g * BT;
  const int u0  = ub * UPB;

  float* sT    = ws + WS_ST;
  float* hrow  = ws + WS_HROW;
  float* cpriv = ws + WS_C + (size_t)bid * (BT * UPB);
  float* kap   = ws + WS_KAP;
  unsigned* fb = (unsigned*)(ws + WS_BAR) + (size_t)g * (12 * 32);
  unsigned* c1 = fb;             // 8 lines: h-ready barrier
  unsigned* c2 = fb + 8 * 32;    // 4 lines: window-ready counter

  __shared__ __align__(16) float wlds[SDIM][RPB]; // weights [k][r], k-major
  __shared__ float xwb[RPB][4];                   // x-weights[3] + bias
  __shared__ float red[NT][17];                   // k-split partials (pad -> conflict-free)
  __shared__ float gl[RPB][BT];
  __shared__ __align__(16) float hl[H_];
  __shared__ float pred[8][30];
  __shared__ float pl[30];
  __shared__ float abk[3][K_];
  __shared__ float phim[U_];                      // phi * mask
  __shared__ float phir[U_];                      // raw phi (for out)
  __shared__ float wl[C_];                        // window (for out)
  __shared__ int   sentl[U_];
  __shared__ float maskl[U_];

  // ---- one-time weight staging ----
  for (int idx = tid; idx < SDIM * RPB; idx += NT) {
    const int k = idx >> 4, r = idx & 15;
    const int uu = r >> 2, gate = r & 3;
    const int gr = gate * H_ + u0 + uu;
    wlds[k][r] = (k < H_) ? W_hh[(size_t)gr * H_ + k]
                          : W_ih[(size_t)gr * (IN_ + C_) + IN_ + (k - H_)];
  }
  if (tid < RPB) {
    const int uu = tid >> 2, gate = tid & 3, gr = gate * H_ + u0 + uu;
    xwb[tid][0] = W_ih[(size_t)gr * (IN_ + C_) + 0];
    xwb[tid][1] = W_ih[(size_t)gr * (IN_ + C_) + 1];
    xwb[tid][2] = W_ih[(size_t)gr * (IN_ + C_) + 2];
    xwb[tid][3] = b_ih[gr] + b_hh[gr];
  }
  const bool isWB = (ub < BT);
  const int  wb_b = b0 + ub;
  if (isWB && tid < U_) {
    sentl[tid] = sent[wb_b * U_ + tid];
    maskl[tid] = smask[wb_b * U_ + tid];
  }
  __syncthreads();

  const int rt  = tid & 3;
  const int bt  = (tid >> 2) & 7;
  const int ks  = tid >> 5;
  const int myb = b0 + 4 * bt;

  for (int t = 0; t < T_; ++t) {
    const int p = t & 1;
    const float* sIn = sT + (size_t)p * (SDIM * B_);
    float*      sOut = sT + (size_t)(1 - p) * (SDIM * B_);

    float acc[4][4];
    #pragma unroll
    for (int i = 0; i < 4; ++i)
      #pragma unroll
      for (int j = 0; j < 4; ++j) acc[i][j] = 0.0f;

    // ---- A1p1: recurrent h-part, k in [0,512). Guarded by bar1(t-1). ----
    {
      const float* sp = sIn + myb;
      const int k0 = ks * (H_ / 8);
      #pragma unroll 4
      for (int k = k0; k < k0 + H_ / 8; ++k) {
        const float4 s4 = *(const float4*)(sp + (size_t)k * B_);
        const float4 w4 = *(const float4*)(&wlds[k][4 * rt]);
        const float sv[4] = {s4.x, s4.y, s4.z, s4.w};
        const float wv[4] = {w4.x, w4.y, w4.z, w4.w};
        #pragma unroll
        for (int i = 0; i < 4; ++i)
          #pragma unroll
          for (int j = 0; j < 4; ++j) acc[i][j] = fmaf(wv[i], sv[j], acc[i][j]);
      }
    }

    // ---- wait for window_{t-1} (relaxed poll, one acquire-inv on success) ----
    if (tid == 0 && t > 0) {
      const unsigned tgt = (unsigned)(BT * t);
      while (flag_sum4(c2) < tgt) __builtin_amdgcn_s_sleep(2);
      acq_fence(c2);
    }
    __syncthreads();

    // ---- A1p2: window part, k in [512,592) ----
    {
      const float* sp = sIn + myb;
      const int k0 = H_ + ks * (C_ / 8);
      #pragma unroll
      for (int k = k0; k < k0 + C_ / 8; ++k) {
        const float4 s4 = *(const float4*)(sp + (size_t)k * B_);
        const float4 w4 = *(const float4*)(&wlds[k][4 * rt]);
        const float sv[4] = {s4.x, s4.y, s4.z, s4.w};
        const float wv[4] = {w4.x, w4.y, w4.z, w4.w};
        #pragma unroll
        for (int i = 0; i < 4; ++i)
          #pragma unroll
          for (int j = 0; j < 4; ++j) acc[i][j] = fmaf(wv[i], sv[j], acc[i][j]);
      }
    }

    // ---- A2: stash k-split partials ----
    #pragma unroll
    for (int i = 0; i < 4; ++i)
      #pragma unroll
      for (int j = 0; j < 4; ++j) red[tid][i * 4 + j] = acc[i][j];
    __syncthreads();

    // ---- A3: reduce over 8 k-splits + bias + x-term ----
    for (int it = tid; it < RPB * BT; it += NT) {
      const int r = it >> 5, b = it & 31;
      const int base = (r >> 2) + 4 * (b >> 2);
      const int e = (r & 3) * 4 + (b & 3);
      float v = xwb[r][3];
      #pragma unroll
      for (int kq = 0; kq < 8; ++kq) v += red[base + 32 * kq][e];
      const float* xp = x + ((size_t)(b0 + b) * T_ + t) * IN_;
      v = fmaf(xwb[r][0], xp[0], v);
      v = fmaf(xwb[r][1], xp[1], v);
      v = fmaf(xwb[r][2], xp[2], v);
      gl[r][b] = v;
    }
    __syncthreads();

    // ---- A4: LSTM pointwise; bypass-publish h (state + transposed row) ----
    if (tid < BT * UPB) {
      const int b = tid >> 2, uu = tid & 3;
      const float iv = sigmoidf_(gl[uu * 4 + 0][b]);
      const float fv = sigmoidf_(gl[uu * 4 + 1][b]);
      const float gv = tanhf(gl[uu * 4 + 2][b]);
      const float ov = sigmoidf_(gl[uu * 4 + 3][b]);
      const float cv = fmaf(fv, cpriv[b * 4 + uu], iv * gv);
      cpriv[b * 4 + uu] = cv;
      const float hv = ov * tanhf(cv);
      st_bypass(&sOut[(size_t)(u0 + uu) * B_ + b0 + b], hv);
      st_bypass(&hrow[(size_t)(b0 + b) * H_ + (u0 + uu)], hv);
    }
    fence_vm();            // per-wave: bypass stores acked at coherence point
    __syncthreads();
    if (tid == 0) flag_add(c1 + (ub & 7) * 32);

    // ---- bar1: all h_t of this group at IF ----
    if (tid == 0) {
      const unsigned tgt = (unsigned)(BPG * (t + 1));
      while (flag_sum8(c1) < tgt) __builtin_amdgcn_s_sleep(2);
      acq_fence(c1);
    }
    __syncthreads();

    // ---- Phase B: window pipeline, one batch per WB block ----
    if (isWB) {
      if (tid < 128)
        *(float4*)&hl[tid * 4] = *(const float4*)(hrow + (size_t)wb_b * H_ + tid * 4);
      __syncthreads();
      if (tid < 240) {                       // p = h @ W_win.T (30 rows x 8 k-chunks)
        const int j = tid % 30, kc = tid / 30;
        const float* wr = W_win + (size_t)j * H_ + kc * 64;
        const float* hp = hl + kc * 64;
        float s = 0.0f;
        #pragma unroll
        for (int k2 = 0; k2 < 64; k2 += 4) {
          const float4 w4 = *(const float4*)(wr + k2);
          s = fmaf(w4.x, hp[k2 + 0], s);
          s = fmaf(w4.y, hp[k2 + 1], s);
          s = fmaf(w4.z, hp[k2 + 2], s);
          s = fmaf(w4.w, hp[k2 + 3], s);
        }
        pred[kc][j] = s;
      }
      __syncthreads();
      if (tid < 30) {
        float s = b_win[tid];
        #pragma unroll
        for (int kc = 0; kc < 8; ++kc) s += pred[kc][tid];
        pl[tid] = s;
      }
      __syncthreads();
      if (tid < K_) {
        abk[0][tid] = expf(pl[tid]);
        abk[1][tid] = expf(pl[K_ + tid]);
        const float kv = kap[tid * B_ + wb_b] + expf(pl[2 * K_ + tid]);
        kap[tid * B_ + wb_b] = kv;
        abk[2][tid] = kv;
      }
      __syncthreads();
      if (tid < U_) {
        const float fu = (float)tid;
        float s = 0.0f;
        #pragma unroll
        for (int j2 = 0; j2 < K_; ++j2) {
          const float d = abk[2][j2] - fu;
          s = fmaf(abk[0][j2], expf(-abk[1][j2] * d * d), s);
        }
        phim[tid] = s * maskl[tid];
        phir[tid] = s;
      }
      __syncthreads();
      if (tid < C_) {                         // window (deterministic gather)
        float wv = 0.0f;
        #pragma unroll
        for (int u = 0; u < U_; ++u) wv += (sentl[u] == tid) ? phim[u] : 0.0f;
        st_bypass(&sOut[(size_t)(H_ + tid) * B_ + wb_b], wv);
        wl[tid] = wv;
      }
      fence_vm();
      __syncthreads();
      if (tid == 0) flag_add(c2 + (ub & 3) * 32);

      // ---- off-critical-path output writes (coalesced, single-writer lines) ----
      if (tid < 128)
        *(float4*)&out[OFF_H + ((size_t)wb_b * T_ + t) * H_ + tid * 4] = *(const float4*)&hl[tid * 4];
      if (tid < U_)
        out[OFF_PHI + ((size_t)wb_b * T_ + t) * U_ + tid] = phir[tid];
      if (tid < C_)
        out[OFF_W + ((size_t)wb_b * T_ + t) * C_ + tid] = wl[tid];
    }
  }
}

extern "C" void kernel_launch(void* const* d_in, const int* in_sizes, int n_in,
                              void* d_out, int out_size, void* d_ws, size_t ws_size,
                              hipStream_t stream) {
  const float* x     = (const float*)d_in[0];
  const int*   sent  = (const int*)  d_in[1];
  const float* smask = (const float*)d_in[2];
  const float* W_ih  = (const float*)d_in[3];
  const float* W_hh  = (const float*)d_in[4];
  const float* b_ih  = (const float*)d_in[5];
  const float* b_hh  = (const float*)d_in[6];
  const float* W_win = (const float*)d_in[7];
  const float* b_win = (const float*)d_in[8];
  float* ws = (float*)d_ws;
  float* out = (float*)d_out;

  hipLaunchKernelGGL(init_ws_kernel, dim3(512), dim3(NT), 0, stream, ws);
  hipLaunchKernelGGL(graves_kernel, dim3(NG * BPG), dim3(NT), 0, stream,
                     x, sent, smask, W_ih, W_hh, b_ih, b_hh, W_win, b_win, out, ws);
}

// Round 4
// 11353.703 us; speedup vs baseline: 5.7247x; 1.4346x over previous
//
#include <hip/hip_runtime.h>
#include <hip/hip_bf16.h>
#include <math.h>

// Problem dims
#define B_   128
#define T_   800
#define H_   512
#define K_   10
#define C_   80
#define U_   64
#define IN_  3
#define SDIM (H_ + C_)   // 592 = h(512) | window(80)

// Decomposition: 4 groups x 32 batches; 64 blocks/group, each owns 8 units (32 gate rows)
#define NG   4
#define BPG  64
#define BT   32
#define UPB  8
#define RPB  32          // gate rows per block (8 units x 4 gates)
#define NT   512

// ws layout (float offsets)
#define WS_ST    0                                   // sT[2][SDIM][B_]
#define WS_GPP   (2*SDIM*B_)                         // p_parts[NG*BPG][BT][30]
#define WS_BAR   (WS_GPP + NG*BPG*BT*30)             // per-group flag lines: 8 x 128B
#define WS_TOTAL (WS_BAR + NG*8*32)

// out layout (f32 elements): h_seq | w_seq | phi_seq
#define OFF_H    0ull
#define OFF_W    ((size_t)B_ * T_ * H_)              // 52,428,800
#define OFF_PHI  (OFF_W + (size_t)B_ * T_ * C_)      // 60,620,800

// ---- sync primitives (round-3 proven): bypass stores + vm fence + relaxed flags ----
__device__ __forceinline__ void st_bypass(float* p, float v) {
  asm volatile("global_store_dword %0, %1, off sc0 sc1" :: "v"(p), "v"(v) : "memory");
}
__device__ __forceinline__ void fence_vm() {
  asm volatile("s_waitcnt vmcnt(0)" ::: "memory");
}
__device__ __forceinline__ void flag_add(unsigned* p) {
  __hip_atomic_fetch_add(p, 1u, __ATOMIC_RELAXED, __HIP_MEMORY_SCOPE_AGENT);
}
__device__ __forceinline__ unsigned flag_sum(unsigned* base, int nlines) {
  unsigned s = 0;
  for (int i = 0; i < nlines; ++i)
    s += __hip_atomic_load(base + i * 32, __ATOMIC_RELAXED, __HIP_MEMORY_SCOPE_AGENT);
  return s;
}
__device__ __forceinline__ void acq_fence(unsigned* p) {
  (void)__hip_atomic_load(p, __ATOMIC_ACQUIRE, __HIP_MEMORY_SCOPE_AGENT);
}
__device__ __forceinline__ float sigmoidf_(float v) { return 1.0f / (1.0f + expf(-v)); }

__global__ void __launch_bounds__(256, 2)
init_ws_kernel(float* __restrict__ ws) {
  size_t i = (size_t)blockIdx.x * 256 + threadIdx.x;
  const size_t n = (size_t)WS_TOTAL;
  const size_t stride = (size_t)gridDim.x * 256;
  for (; i < n; i += stride) ws[i] = 0.0f;
}

__global__ void __launch_bounds__(NT, 1)
graves_kernel(const float* __restrict__ x,       // [B][T][IN]
              const int*   __restrict__ sent,    // [B][U]
              const float* __restrict__ smask,   // [B][U]
              const float* __restrict__ W_ih,    // [2048][83]
              const float* __restrict__ W_hh,    // [2048][512]
              const float* __restrict__ b_ih,    // [2048]
              const float* __restrict__ b_hh,    // [2048]
              const float* __restrict__ W_win,   // [30][512]
              const float* __restrict__ b_win,   // [30]
              float* __restrict__ out,
              float* __restrict__ ws)
{
  const int tid = threadIdx.x;
  const int bid = blockIdx.x;
  const int g   = bid / BPG;         // contiguous blocks per group -> co-resident
  const int ub  = bid - g * BPG;
  const int b0  = g * BT;
  const int u0  = ub * UPB;

  float* sT  = ws + WS_ST;
  float* gpp = ws + WS_GPP;
  unsigned* fb = (unsigned*)(ws + WS_BAR) + (size_t)g * (8 * 32);
  unsigned* c1 = fb;             // 4 lines: h-ready barrier (64 arrivals)
  unsigned* c2 = fb + 4 * 32;    // 2 lines: window-ready (32 arrivals)

  // ---- LDS (~127.5 KB total, 1 block/CU) ----
  __shared__ __align__(16) float wlds[SDIM][RPB];   // 75,776 B  [k][r]
  __shared__ float red[NT][17];                     // 34,816 B  k-split partials
  __shared__ float gl[RPB][BT];                     //  4,096 B  gates
  __shared__ float hT[UPB][BT];                     //  1,024 B  h of this block's units
  __shared__ float cpl[UPB][BT];                    //  1,024 B  c-state (persistent)
  __shared__ float wwin[UPB][30];                   //    960 B  W_win slice
  __shared__ float xwb[RPB][4];                     //    512 B  x-weights + bias
  __shared__ float ppst[BPG][30];                   //  7,680 B  p-part staging (WB)
  __shared__ float pl[30];
  __shared__ float abk[3][K_];
  __shared__ float kapl[K_];                        // kappa (persistent, WB)
  __shared__ float phim[U_];
  __shared__ float phir[U_];
  __shared__ float wl[C_];
  __shared__ int   sentl[U_];
  __shared__ float maskl[U_];

  // ---- one-time staging ----
  for (int idx = tid; idx < SDIM * RPB; idx += NT) {
    const int k = idx >> 5, r = idx & 31;
    const int uu = r >> 2, gate = r & 3;
    const int gr = gate * H_ + u0 + uu;
    wlds[k][r] = (k < H_) ? W_hh[(size_t)gr * H_ + k]
                          : W_ih[(size_t)gr * (IN_ + C_) + IN_ + (k - H_)];
  }
  if (tid < RPB) {
    const int uu = tid >> 2, gate = tid & 3, gr = gate * H_ + u0 + uu;
    xwb[tid][0] = W_ih[(size_t)gr * (IN_ + C_) + 0];
    xwb[tid][1] = W_ih[(size_t)gr * (IN_ + C_) + 1];
    xwb[tid][2] = W_ih[(size_t)gr * (IN_ + C_) + 2];
    xwb[tid][3] = b_ih[gr] + b_hh[gr];
  }
  if (tid < UPB * 30) {            // W_win slice for p-partials
    const int uu = tid / 30, j = tid % 30;
    wwin[uu][j] = W_win[(size_t)j * H_ + u0 + uu];
  }
  if (tid < UPB * BT) {            // c-state init
    cpl[tid >> 5][tid & 31] = 0.0f;
  }
  const bool isWB = (ub < BT);     // first 32 blocks own one batch's window finish
  const int  wb_b = b0 + ub;
  if (isWB) {
    if (tid < U_) {
      sentl[tid] = sent[wb_b * U_ + tid];
      maskl[tid] = smask[wb_b * U_ + tid];
    }
    if (tid < K_) kapl[tid] = 0.0f;
  }
  __syncthreads();

  const int rt  = tid & 7;          // row tile: rows 4*rt..4*rt+3
  const int bt  = (tid >> 3) & 7;   // batch tile: batches 4*bt..4*bt+3
  const int ks  = tid >> 6;         // k split (8 chunks; wave-uniform)
  const int myb = b0 + 4 * bt;

  for (int t = 0; t < T_; ++t) {
    const int p = t & 1;
    const float* sIn = sT + (size_t)p * (SDIM * B_);
    float*      sOut = sT + (size_t)(1 - p) * (SDIM * B_);

    float acc[4][4];
    #pragma unroll
    for (int i = 0; i < 4; ++i)
      #pragma unroll
      for (int j = 0; j < 4; ++j) acc[i][j] = 0.0f;

    // ---- A1p1: h-part, k in [0,512). Guarded by bar1(t-1); overlaps Phase B(t-1). ----
    {
      const float* sp = sIn + myb;
      const int k0 = ks * (H_ / 8);
      #pragma unroll 4
      for (int k = k0; k < k0 + H_ / 8; ++k) {
        const float4 s4 = *(const float4*)(sp + (size_t)k * B_);
        const float4 w4 = *(const float4*)(&wlds[k][4 * rt]);
        const float sv[4] = {s4.x, s4.y, s4.z, s4.w};
        const float wv[4] = {w4.x, w4.y, w4.z, w4.w};
        #pragma unroll
        for (int i = 0; i < 4; ++i)
          #pragma unroll
          for (int j = 0; j < 4; ++j) acc[i][j] = fmaf(wv[i], sv[j], acc[i][j]);
      }
    }

    // ---- wait for window_{t-1} ----
    if (tid == 0 && t > 0) {
      const unsigned tgt = (unsigned)(BT * t);
      while (flag_sum(c2, 2) < tgt) __builtin_amdgcn_s_sleep(1);
      acq_fence(c2);
    }
    __syncthreads();

    // ---- A1p2: window part, k in [512,592) ----
    {
      const float* sp = sIn + myb;
      const int k0 = H_ + ks * (C_ / 8);
      #pragma unroll
      for (int k = k0; k < k0 + C_ / 8; ++k) {
        const float4 s4 = *(const float4*)(sp + (size_t)k * B_);
        const float4 w4 = *(const float4*)(&wlds[k][4 * rt]);
        const float sv[4] = {s4.x, s4.y, s4.z, s4.w};
        const float wv[4] = {w4.x, w4.y, w4.z, w4.w};
        #pragma unroll
        for (int i = 0; i < 4; ++i)
          #pragma unroll
          for (int j = 0; j < 4; ++j) acc[i][j] = fmaf(wv[i], sv[j], acc[i][j]);
      }
    }

    // ---- A2: stash k-split partials ----
    #pragma unroll
    for (int i = 0; i < 4; ++i)
      #pragma unroll
      for (int j = 0; j < 4; ++j) red[tid][i * 4 + j] = acc[i][j];
    __syncthreads();

    // ---- A3: reduce 8 k-splits + bias + x ----
    for (int it = tid; it < RPB * BT; it += NT) {
      const int r = it >> 5, b = it & 31;
      const int base = (r >> 2) + 8 * (b >> 2);
      const int e = (r & 3) * 4 + (b & 3);
      float v = xwb[r][3];
      #pragma unroll
      for (int kq = 0; kq < 8; ++kq) v += red[base + 64 * kq][e];
      const float* xp = x + ((size_t)(b0 + b) * T_ + t) * IN_;
      v = fmaf(xwb[r][0], xp[0], v);
      v = fmaf(xwb[r][1], xp[1], v);
      v = fmaf(xwb[r][2], xp[2], v);
      gl[r][b] = v;
    }
    __syncthreads();

    // ---- A4: LSTM pointwise (256 items: 32 b x 8 u); publish h ----
    if (tid < BT * UPB) {
      const int b = tid & 31, uu = tid >> 5;
      const float iv = sigmoidf_(gl[uu * 4 + 0][b]);
      const float fv = sigmoidf_(gl[uu * 4 + 1][b]);
      const float gv = tanhf(gl[uu * 4 + 2][b]);
      const float ov = sigmoidf_(gl[uu * 4 + 3][b]);
      const float cv = fmaf(fv, cpl[uu][b], iv * gv);
      cpl[uu][b] = cv;
      const float hv = ov * tanhf(cv);
      hT[uu][b] = hv;
      st_bypass(&sOut[(size_t)(u0 + uu) * B_ + b0 + b], hv);
    }
    __syncthreads();

    // ---- p-partials: this block's 8-unit contribution to p[b][30] ----
    for (int it = tid; it < BT * 30; it += NT) {
      const int b = it / 30, j = it % 30;
      float s = 0.0f;
      #pragma unroll
      for (int uu = 0; uu < UPB; ++uu) s = fmaf(wwin[uu][j], hT[uu][b], s);
      st_bypass(&gpp[((size_t)(g * BPG + ub) * BT + b) * 30 + j], s);
    }
    fence_vm();
    __syncthreads();
    if (tid == 0) flag_add(c1 + (ub & 3) * 32);

    if (!isWB) {
      // h output (off critical path), then wait bar1
      if (tid < 64) {
        const int b = tid >> 1, half = tid & 1;
        float4 hv4 = make_float4(hT[half * 4 + 0][b], hT[half * 4 + 1][b],
                                 hT[half * 4 + 2][b], hT[half * 4 + 3][b]);
        *(float4*)&out[OFF_H + ((size_t)(b0 + b) * T_ + t) * H_ + u0 + half * 4] = hv4;
      }
      if (tid == 0) {
        const unsigned tgt = (unsigned)(BPG * (t + 1));
        while (flag_sum(c1, 4) < tgt) __builtin_amdgcn_s_sleep(1);
        acq_fence(c1);
      }
      __syncthreads();
    } else {
      // ---- Phase B: finish window for batch wb_b ----
      if (tid == 0) {
        const unsigned tgt = (unsigned)(BPG * (t + 1));
        while (flag_sum(c1, 4) < tgt) __builtin_amdgcn_s_sleep(1);
        acq_fence(c1);
      }
      __syncthreads();
      for (int it = tid; it < BPG * 30; it += NT) {      // read 64 blocks' partials
        const int blk = it / 30, j = it % 30;
        ppst[blk][j] = gpp[((size_t)(g * BPG + blk) * BT + ub) * 30 + j];
      }
      __syncthreads();
      if (tid < 30) {
        float s = b_win[tid];
        #pragma unroll
        for (int blk = 0; blk < BPG; ++blk) s += ppst[blk][tid];
        pl[tid] = s;
      }
      __syncthreads();
      if (tid < K_) {
        abk[0][tid] = expf(pl[tid]);                     // alpha
        abk[1][tid] = expf(pl[K_ + tid]);                // beta
        const float kv = kapl[tid] + expf(pl[2 * K_ + tid]);
        kapl[tid] = kv;                                  // kappa (LDS-persistent)
        abk[2][tid] = kv;
      }
      __syncthreads();
      if (tid < U_) {
        const float fu = (float)tid;
        float s = 0.0f;
        #pragma unroll
        for (int j2 = 0; j2 < K_; ++j2) {
          const float d = abk[2][j2] - fu;
          s = fmaf(abk[0][j2], expf(-abk[1][j2] * d * d), s);
        }
        phim[tid] = s * maskl[tid];
        phir[tid] = s;
      }
      __syncthreads();
      if (tid < C_) {                                    // window gather
        float wv = 0.0f;
        #pragma unroll
        for (int u = 0; u < U_; ++u) wv += (sentl[u] == tid) ? phim[u] : 0.0f;
        st_bypass(&sOut[(size_t)(H_ + tid) * B_ + wb_b], wv);
        wl[tid] = wv;
      }
      fence_vm();
      __syncthreads();
      if (tid == 0) flag_add(c2 + (ub & 1) * 32);

      // outputs (off critical path)
      if (tid < 64) {
        const int b = tid >> 1, half = tid & 1;
        float4 hv4 = make_float4(hT[half * 4 + 0][b], hT[half * 4 + 1][b],
                                 hT[half * 4 + 2][b], hT[half * 4 + 3][b]);
        *(float4*)&out[OFF_H + ((size_t)(b0 + b) * T_ + t) * H_ + u0 + half * 4] = hv4;
      }
      if (tid < U_) out[OFF_PHI + ((size_t)wb_b * T_ + t) * U_ + tid] = phir[tid];
      if (tid < C_) out[OFF_W + ((size_t)wb_b * T_ + t) * C_ + tid] = wl[tid];
    }
  }
}

extern "C" void kernel_launch(void* const* d_in, const int* in_sizes, int n_in,
                              void* d_out, int out_size, void* d_ws, size_t ws_size,
                              hipStream_t stream) {
  const float* x     = (const float*)d_in[0];
  const int*   sent  = (const int*)  d_in[1];
  const float* smask = (const float*)d_in[2];
  const float* W_ih  = (const float*)d_in[3];
  const float* W_hh  = (const float*)d_in[4];
  const float* b_ih  = (const float*)d_in[5];
  const float* b_hh  = (const float*)d_in[6];
  const float* W_win = (const float*)d_in[7];
  const float* b_win = (const float*)d_in[8];
  float* ws = (float*)d_ws;
  float* out = (float*)d_out;

  hipLaunchKernelGGL(init_ws_kernel, dim3(512), dim3(256), 0, stream, ws);
  hipLaunchKernelGGL(graves_kernel, dim3(NG * BPG), dim3(NT), 0, stream,
                     x, sent, smask, W_ih, W_hh, b_ih, b_hh, W_win, b_win, out, ws);
}

// Round 5
// 10540.250 us; speedup vs baseline: 6.1665x; 1.0772x over previous
//
#include <hip/hip_runtime.h>
#include <hip/hip_bf16.h>
#include <math.h>

// Problem dims
#define B_   128
#define T_   800
#define H_   512
#define K_   10
#define C_   80
#define U_   64
#define IN_  3

// Decomposition: 4 groups x 32 batches; 64 blocks/group; each block owns 8 units (32 gate rows)
#define NG   4
#define BPG  64
#define BT   32
#define NT   256
#define KROW 608            // padded K extent (592 real + 16 zero)

// ws layout (4-byte units): gbuf[2][128][608] u32 | gpp[256][32][30] f32 | flags
#define WS_GPP_F (2*B_*KROW)
#define WS_BAR_F (WS_GPP_F + NG*BPG*BT*30)
#define WS_TOTAL_F (WS_BAR_F + NG*8*32)

// out layout (f32 elements): h_seq | w_seq | phi_seq
#define OFF_H    0ull
#define OFF_W    ((size_t)B_ * T_ * H_)
#define OFF_PHI  (OFF_W + (size_t)B_ * T_ * C_)

typedef __attribute__((ext_vector_type(8))) short short8;
typedef __attribute__((ext_vector_type(4))) float f32x4;

// XOR swizzle of 16B units within each 64B span, keyed by row -> bank-optimal frag reads
#define SWZB(row)    (((row) ^ ((row) >> 2)) & 3)
#define SWIDX(row,k) ((row)*KROW + ((((k) >> 3) ^ SWZB(row)) << 3) + ((k) & 7))
#define LDFRAG(arr,row,u) (*(const short8*)&(arr)[(row)*KROW + (((u) ^ SWZB(row)) << 3)])

// ---- sync primitives (round-3/4 proven): bypass stores + vm fence + relaxed flags ----
__device__ __forceinline__ void stb_f32(float* p, float v) {
  asm volatile("global_store_dword %0, %1, off sc0 sc1" :: "v"(p), "v"(v) : "memory");
}
__device__ __forceinline__ void stb_u32(unsigned* p, unsigned v) {
  asm volatile("global_store_dword %0, %1, off sc0 sc1" :: "v"(p), "v"(v) : "memory");
}
__device__ __forceinline__ void fence_vm() {
  asm volatile("s_waitcnt vmcnt(0)" ::: "memory");
}
__device__ __forceinline__ void flag_add(unsigned* p) {
  __hip_atomic_fetch_add(p, 1u, __ATOMIC_RELAXED, __HIP_MEMORY_SCOPE_AGENT);
}
__device__ __forceinline__ unsigned flag_sum(unsigned* base, int nlines) {
  unsigned s = 0;
  for (int i = 0; i < nlines; ++i)
    s += __hip_atomic_load(base + i * 32, __ATOMIC_RELAXED, __HIP_MEMORY_SCOPE_AGENT);
  return s;
}
__device__ __forceinline__ void acq_fence(unsigned* p) {
  (void)__hip_atomic_load(p, __ATOMIC_ACQUIRE, __HIP_MEMORY_SCOPE_AGENT);
}
__device__ __forceinline__ float sigmoidf_(float v) { return 1.0f / (1.0f + expf(-v)); }
__device__ __forceinline__ unsigned pack_hl(float v) {
  unsigned hb = __float_as_uint(v) >> 16;
  float rs = v - __uint_as_float(hb << 16);
  unsigned lb = __float_as_uint(rs) >> 16;
  return (hb << 16) | lb;
}

__global__ void __launch_bounds__(256, 2)
init_ws_kernel(float* __restrict__ ws) {
  size_t i = (size_t)blockIdx.x * 256 + threadIdx.x;
  const size_t n = (size_t)WS_TOTAL_F;
  const size_t stride = (size_t)gridDim.x * 256;
  for (; i < n; i += stride) ws[i] = 0.0f;
}

__global__ void __launch_bounds__(NT, 1)
graves_kernel(const float* __restrict__ x,       // [B][T][3]
              const int*   __restrict__ sent,    // [B][U]
              const float* __restrict__ smask,   // [B][U]
              const float* __restrict__ W_ih,    // [2048][83]
              const float* __restrict__ W_hh,    // [2048][512]
              const float* __restrict__ b_ih,    // [2048]
              const float* __restrict__ b_hh,    // [2048]
              const float* __restrict__ W_win,   // [30][512]
              const float* __restrict__ b_win,   // [30]
              float* __restrict__ out,
              float* __restrict__ ws)
{
  const int tid = threadIdx.x;
  const int bid = blockIdx.x;
  const int g   = bid >> 6;          // group (64 blocks each, contiguous)
  const int ub  = bid & (BPG - 1);
  const int b0  = g * BT;
  const int u0  = ub * 8;            // first unit owned

  unsigned* gbufu = (unsigned*)ws;
  float*    gpp   = ws + WS_GPP_F;
  unsigned* fb    = (unsigned*)(ws + WS_BAR_F) + (size_t)g * 256;
  unsigned* c1l   = fb;              // 4 lines, 64 arrivals/step
  unsigned* c2l   = fb + 4 * 32;     // 2 lines, 32 arrivals/step

  // ---- LDS: 162,792 B total -> 1 block/CU ----
  __shared__ __align__(16) short whi[32 * KROW];   // 38,912 B  W hi (swizzled)
  __shared__ __align__(16) short wlo[32 * KROW];   // 38,912 B  W lo
  __shared__ __align__(16) short shi[32 * KROW];   // 38,912 B  state hi
  __shared__ __align__(16) short slo[32 * KROW];   // 38,912 B  state lo
  __shared__ __align__(16) float glf[1024];        //  4,096 B  k-reduce tiles / PhaseB scratch (time-disjoint)
  __shared__ float hT[8 * 32];                     //  1,024 B  h of this block's units
  __shared__ float wwin[8 * 30];                   //    960 B  W_win slice
  __shared__ float xwb[32 * 4];                    //    512 B  x-weights + bias
  __shared__ int   sentl[U_];                      //    256 B
  __shared__ float maskl[U_];                      //    256 B
  __shared__ float kapl[K_ + 6];                   //     64 B  kappa (persistent, WB)

  float* pred  = glf;          // [8][30]
  float* pl    = glf + 256;    // [30]
  float* abkA  = glf + 288;    // alpha[10]
  float* abkB  = glf + 304;    // beta[10]
  float* abkK  = glf + 320;    // kappa[10]
  float* phim  = glf + 336;    // [64]

  // ---- one-time staging ----
  for (int idx = tid; idx < 32 * KROW; idx += NT) {
    const int r = idx / KROW, k = idx - r * KROW;
    const int uu = r >> 2, gate = r & 3, gr = gate * H_ + u0 + uu;
    float wv = 0.0f;
    if (k < H_)      wv = W_hh[(size_t)gr * H_ + k];
    else if (k < H_ + C_) wv = W_ih[(size_t)gr * (IN_ + C_) + IN_ + (k - H_)];
    const unsigned hb = __float_as_uint(wv) >> 16;
    const float rs = wv - __uint_as_float(hb << 16);
    const unsigned lb = __float_as_uint(rs) >> 16;
    const int li = SWIDX(r, k);
    whi[li] = (short)hb;
    wlo[li] = (short)lb;
  }
  for (int idx = tid; idx < 32 * 16; idx += NT) {  // zero state pad (never rewritten)
    const int b2 = idx >> 4, k = (H_ + C_) + (idx & 15);
    shi[SWIDX(b2, k)] = 0; slo[SWIDX(b2, k)] = 0;
  }
  if (tid < 32) {
    const int uu = tid >> 2, gate = tid & 3, gr = gate * H_ + u0 + uu;
    xwb[tid * 4 + 0] = W_ih[(size_t)gr * (IN_ + C_) + 0];
    xwb[tid * 4 + 1] = W_ih[(size_t)gr * (IN_ + C_) + 1];
    xwb[tid * 4 + 2] = W_ih[(size_t)gr * (IN_ + C_) + 2];
    xwb[tid * 4 + 3] = b_ih[gr] + b_hh[gr];
  }
  for (int idx = tid; idx < 240; idx += NT) {
    const int uu = idx / 30, j = idx - uu * 30;
    wwin[idx] = W_win[(size_t)j * H_ + u0 + uu];
  }
  const bool isWB = (ub < BT);
  const int  wb_b = b0 + ub;
  if (isWB) {
    if (tid < U_) { sentl[tid] = sent[wb_b * U_ + tid]; maskl[tid] = smask[wb_b * U_ + tid]; }
    if (tid < K_) kapl[tid] = 0.0f;
  }
  __syncthreads();

  // wave identity
  const int lane = tid & 63;
  const int wid  = tid >> 6;         // 0..3
  const int ni   = wid & 1;          // batch-tile
  const int kh   = wid >> 1;         // k-half; kh==0 waves own outputs
  const int r16  = lane & 15;
  const int g4   = lane >> 4;
  const int bb   = ni * 16 + r16;    // batch-local for B-frags / A4

  float cr0 = 0.0f, cr1 = 0.0f;      // c-state in registers (kh==0 lanes)

#define GSTEP(ks) { \
    const int uu_ = (ks) * 4 + g4; \
    const short8 bh = LDFRAG(shi, bb, uu_); \
    const short8 bl = LDFRAG(slo, bb, uu_); \
    const short8 ah0 = LDFRAG(whi, r16, uu_); \
    const short8 al0 = LDFRAG(wlo, r16, uu_); \
    const short8 ah1 = LDFRAG(whi, 16 + r16, uu_); \
    const short8 al1 = LDFRAG(wlo, 16 + r16, uu_); \
    a0 = __builtin_amdgcn_mfma_f32_16x16x32_bf16(ah0, bh, a0, 0, 0, 0); \
    a0 = __builtin_amdgcn_mfma_f32_16x16x32_bf16(ah0, bl, a0, 0, 0, 0); \
    a0 = __builtin_amdgcn_mfma_f32_16x16x32_bf16(al0, bh, a0, 0, 0, 0); \
    a1 = __builtin_amdgcn_mfma_f32_16x16x32_bf16(ah1, bh, a1, 0, 0, 0); \
    a1 = __builtin_amdgcn_mfma_f32_16x16x32_bf16(ah1, bl, a1, 0, 0, 0); \
    a1 = __builtin_amdgcn_mfma_f32_16x16x32_bf16(al1, bh, a1, 0, 0, 0); \
  }

  for (int t = 0; t <= T_; ++t) {
    if (!isWB && t == T_) break;     // non-WB blocks fully done

    const unsigned* pIn  = gbufu + (size_t)((t & 1) ^ 1) * (B_ * KROW); // state(t-1)
    unsigned*       pInW = gbufu + (size_t)((t & 1) ^ 1) * (B_ * KROW);
    unsigned*       pOut = gbufu + (size_t)(t & 1) * (B_ * KROW);       // state(t)

    // ---- P1: wait all h(t-1)+p-partials published ----
    if (tid == 0 && t > 0) {
      const unsigned tgt = 64u * (unsigned)t;
      while (flag_sum(c1l, 4) < tgt) __builtin_amdgcn_s_sleep(1);
      acq_fence(c1l);
    }
    __syncthreads();

    // ---- P2: stage h-state (cols 0..511) into LDS; prefetch x; WB loads p-partials ----
    float xv0 = 0.f, xv1 = 0.f, xv2 = 0.f;
    float pv0=0,pv1=0,pv2=0,pv3=0,pv4=0,pv5=0,pv6=0,pv7=0;
    if (t < T_) {
      const int sb = tid & 31, seg = tid >> 5;
      const unsigned* grow = pIn + (size_t)(b0 + sb) * KROW + seg * 64;
      uint4 v[16];
      #pragma unroll
      for (int i = 0; i < 16; ++i) v[i] = *(const uint4*)(grow + i * 4);
      #pragma unroll
      for (int i = 0; i < 16; ++i) {
        const int k = seg * 64 + i * 4;
        const int idx = SWIDX(sb, k);
        const unsigned h01 = (v[i].x >> 16) | ((v[i].y >> 16) << 16);
        const unsigned h23 = (v[i].z >> 16) | ((v[i].w >> 16) << 16);
        const unsigned l01 = (v[i].x & 0xffffu) | ((v[i].y & 0xffffu) << 16);
        const unsigned l23 = (v[i].z & 0xffffu) | ((v[i].w & 0xffffu) << 16);
        *(uint2*)&shi[idx] = make_uint2(h01, h23);
        *(uint2*)&slo[idx] = make_uint2(l01, l23);
      }
      if (kh == 0) {
        const float* xp = x + ((size_t)(b0 + bb) * T_ + t) * IN_;
        xv0 = xp[0]; xv1 = xp[1]; xv2 = xp[2];
      }
    }
    if (isWB && t >= 1 && tid < 240) {
      const int j = tid % 30, ch = tid / 30;
      const float* gp = gpp + (((size_t)(g * BPG + ch * 8) * BT + ub) * 30 + j);
      pv0 = gp[0*BT*30]; pv1 = gp[1*BT*30]; pv2 = gp[2*BT*30]; pv3 = gp[3*BT*30];
      pv4 = gp[4*BT*30]; pv5 = gp[5*BT*30]; pv6 = gp[6*BT*30]; pv7 = gp[7*BT*30];
    }
    __syncthreads();

    // ---- P3: WB Phase B -> window(t-1), published EARLY (before own GEMM) ----
    if (isWB && t >= 1) {
      if (tid < 240) pred[tid] = ((pv0+pv1)+(pv2+pv3))+((pv4+pv5)+(pv6+pv7));
      __syncthreads();
      if (tid < 30) {
        float s = b_win[tid];
        #pragma unroll
        for (int ch = 0; ch < 8; ++ch) s += pred[ch * 30 + tid];
        pl[tid] = s;
      }
      __syncthreads();
      if (tid < K_) {
        abkA[tid] = expf(pl[tid]);
        abkB[tid] = expf(pl[K_ + tid]);
        const float kv = kapl[tid] + expf(pl[2 * K_ + tid]);
        kapl[tid] = kv;
        abkK[tid] = kv;
      }
      __syncthreads();
      if (tid < U_) {
        const float fu = (float)tid;
        float s = 0.0f;
        #pragma unroll
        for (int j2 = 0; j2 < K_; ++j2) {
          const float d = abkK[j2] - fu;
          s = fmaf(abkA[j2], expf(-abkB[j2] * d * d), s);
        }
        phim[tid] = s * maskl[tid];
        out[OFF_PHI + ((size_t)wb_b * T_ + (t - 1)) * U_ + tid] = s;
      }
      __syncthreads();
      if (tid < C_) {
        float wv = 0.0f;
        #pragma unroll
        for (int u = 0; u < U_; ++u) wv += (sentl[u] == tid) ? phim[u] : 0.0f;
        stb_u32(&pInW[(size_t)wb_b * KROW + H_ + tid], pack_hl(wv));
        out[OFF_W + ((size_t)wb_b * T_ + (t - 1)) * C_ + tid] = wv;
      }
      fence_vm();
      __syncthreads();
      if (tid == 0) flag_add(c2l + (ub & 1) * 32);
    }
    if (t == T_) break;              // WB epilogue done

    // ---- P4: GEMM over h-part (k 0..511), split-bf16, kh halves ----
    f32x4 a0 = {0.f, 0.f, 0.f, 0.f}, a1 = {0.f, 0.f, 0.f, 0.f};
    for (int ks = kh * 8; ks < kh * 8 + 8; ++ks) GSTEP(ks);

    // ---- P5: wait window(t-1) published ----
    if (tid == 0 && t > 0) {
      const unsigned tgt = 32u * (unsigned)t;
      while (flag_sum(c2l, 2) < tgt) __builtin_amdgcn_s_sleep(1);
      acq_fence(c2l);
    }
    __syncthreads();

    // ---- P6: stage window cols (512..591) ----
    {
      const int sb = tid & 31, seg = tid >> 5;
      #pragma unroll
      for (int i = 0; i < 10; ++i) {
        const int c = seg * 10 + i;
        const unsigned v = pIn[(size_t)(b0 + sb) * KROW + H_ + c];
        const int idx = SWIDX(sb, H_ + c);
        shi[idx] = (short)(v >> 16);
        slo[idx] = (short)(v & 0xffffu);
      }
    }
    __syncthreads();

    // ---- P7: GEMM tail (k 512..607, pad zeros) ----
    if (kh == 0) { GSTEP(16); }
    else         { GSTEP(17); GSTEP(18); }

    // ---- P8: cross-kh reduce, LSTM pointwise in-register, publish h ----
    if (kh == 1) {
      #pragma unroll
      for (int e = 0; e < 4; ++e) {
        glf[(ni * 2 + 0) * 256 + (g4 * 4 + e) * 16 + r16] = a0[e];
        glf[(ni * 2 + 1) * 256 + (g4 * 4 + e) * 16 + r16] = a1[e];
      }
    }
    __syncthreads();
    if (kh == 0) {
      #pragma unroll
      for (int mi = 0; mi < 2; ++mi) {
        float ge[4];
        #pragma unroll
        for (int e = 0; e < 4; ++e) {
          const int r = mi * 16 + g4 * 4 + e;
          const float av = ((mi == 0) ? a0[e] : a1[e]) + glf[(ni * 2 + mi) * 256 + (g4 * 4 + e) * 16 + r16];
          ge[e] = av + xwb[r*4+0]*xv0 + xwb[r*4+1]*xv1 + xwb[r*4+2]*xv2 + xwb[r*4+3];
        }
        const float iv = sigmoidf_(ge[0]);
        const float fv = sigmoidf_(ge[1]);
        const float gv = tanhf(ge[2]);
        const float ov = sigmoidf_(ge[3]);
        const float cprev = (mi == 0) ? cr0 : cr1;
        const float cv = fmaf(fv, cprev, iv * gv);
        if (mi == 0) cr0 = cv; else cr1 = cv;
        const float hv = ov * tanhf(cv);
        const int uu = mi * 4 + g4;
        hT[uu * 32 + bb] = hv;
        stb_u32(&pOut[(size_t)(b0 + bb) * KROW + (u0 + uu)], pack_hl(hv));
        out[OFF_H + ((size_t)(b0 + bb) * T_ + t) * H_ + (u0 + uu)] = hv;
      }
    }
    __syncthreads();

    // ---- P9: p-partials (this block's 8-unit contribution), publish + flag ----
    for (int it = tid; it < BT * 30; it += NT) {
      const int b2 = it / 30, j = it - b2 * 30;
      float s = 0.0f;
      #pragma unroll
      for (int uu = 0; uu < 8; ++uu) s = fmaf(wwin[uu * 30 + j], hT[uu * 32 + b2], s);
      stb_f32(&gpp[((size_t)bid * BT + b2) * 30 + j], s);
    }
    fence_vm();
    __syncthreads();
    if (tid == 0) flag_add(c1l + (ub & 3) * 32);
  }
#undef GSTEP
}

extern "C" void kernel_launch(void* const* d_in, const int* in_sizes, int n_in,
                              void* d_out, int out_size, void* d_ws, size_t ws_size,
                              hipStream_t stream) {
  const float* x     = (const float*)d_in[0];
  const int*   sent  = (const int*)  d_in[1];
  const float* smask = (const float*)d_in[2];
  const float* W_ih  = (const float*)d_in[3];
  const float* W_hh  = (const float*)d_in[4];
  const float* b_ih  = (const float*)d_in[5];
  const float* b_hh  = (const float*)d_in[6];
  const float* W_win = (const float*)d_in[7];
  const float* b_win = (const float*)d_in[8];
  float* ws  = (float*)d_ws;
  float* out = (float*)d_out;

  hipLaunchKernelGGL(init_ws_kernel, dim3(512), dim3(256), 0, stream, ws);
  hipLaunchKernelGGL(graves_kernel, dim3(NG * BPG), dim3(NT), 0, stream,
                     x, sent, smask, W_ih, W_hh, b_ih, b_hh, W_win, b_win, out, ws);
}